// Round 8
// baseline (254.216 us; speedup 1.0000x reference)
//
#include <hip/hip_runtime.h>
#include <hip/hip_cooperative_groups.h>
#include <cstddef>

namespace cg = cooperative_groups;

#define NN 512
#define NEG_SLOPE 0.2f

typedef __attribute__((ext_vector_type(8))) short short8;
typedef __attribute__((ext_vector_type(16))) float f32x16;

__device__ __forceinline__ unsigned short f2bf(float v) {
  unsigned u = __float_as_uint(v);
  return (unsigned short)((u + 0x7FFFu + ((u >> 16) & 1u)) >> 16);
}

// ---------------- K0: tiny weight prep (unchanged, proven R6)
__global__ __launch_bounds__(256) void k_prep(const float* __restrict__ W1,
                                              const float* __restrict__ W2,
                                              short8* __restrict__ W1B,
                                              short8* __restrict__ W2B) {
  int blk = blockIdx.x, t = threadIdx.x;
  if (blk < 8) {
    int idx = blk * 256 + t;
    int unit = idx >> 6, lane = idx & 63;
    int nt = unit >> 2, kt = unit & 3;
    int f = nt * 32 + (lane & 31);
    int k0 = kt * 16 + ((lane >> 5) << 3);
    short8 r;
#pragma unroll
    for (int j = 0; j < 8; ++j) r[j] = (short)f2bf(W1[(k0 + j) * 256 + f]);
    W1B[idx] = r;
  } else {
    int idx = (blk - 8) * 256 + t;
    int unit = idx >> 6, lane = idx & 63;
    int nt = unit >> 4, kt = unit & 15;
    int f = nt * 32 + (lane & 31);
    int k0 = kt * 16 + ((lane >> 5) << 3);
    short8 r;
#pragma unroll
    for (int j = 0; j < 8; ++j) r[j] = (short)f2bf(W2[(k0 + j) * 64 + f]);
    W2B[idx] = r;
  }
}

// ================= Phase 1: mask (waves 1-3, -> global) + gemm1 (wave 0)
__device__ __forceinline__ void phase1(int i, int t, char* smem,
                                       const int* __restrict__ adj,
                                       const float* __restrict__ x,
                                       const short8* __restrict__ W1B,
                                       const float* __restrict__ a1s,
                                       const float* __restrict__ a1d,
                                       unsigned* __restrict__ mask,
                                       unsigned short* __restrict__ hb1,
                                       float* __restrict__ e1s,
                                       float* __restrict__ e1d) {
  int b = (i & 7) * 4 + ((i >> 3) & 3), mt = i >> 5;  // XCD-affine swizzle
  int d0 = mt * 32;
  if (t >= 64) {
    int t2 = t - 64;
    const int* abase = adj + (size_t)b * NN * NN;
    for (int u = t2; u < 512; u += 192) {
      int dl = u & 31, w = u >> 5;
      int d = d0 + dl;
      unsigned wv = 0;
#pragma unroll
      for (int j = 0; j < 32; ++j) {
        int s = w * 32 + j;
        unsigned bit = ((abase[(size_t)s * NN + d] != 0) || (s == d)) ? 1u : 0u;
        wv |= bit << j;
      }
      mask[((size_t)b * 16 + w) * NN + d] = wv;
    }
  } else {
    float* tile = (float*)smem;  // 32x36 fp32
    int lane = t, m = lane & 31, kg = lane >> 5;
    const float* xrow = x + ((size_t)b * NN + d0 + m) * 64 + kg * 8;
    short8 a[4];
#pragma unroll
    for (int kt = 0; kt < 4; ++kt) {
      float4 v0 = *(const float4*)(xrow + kt * 16);
      float4 v1 = *(const float4*)(xrow + kt * 16 + 4);
      short8 r;
      r[0] = (short)f2bf(v0.x); r[1] = (short)f2bf(v0.y);
      r[2] = (short)f2bf(v0.z); r[3] = (short)f2bf(v0.w);
      r[4] = (short)f2bf(v1.x); r[5] = (short)f2bf(v1.y);
      r[6] = (short)f2bf(v1.z); r[7] = (short)f2bf(v1.w);
      a[kt] = r;
    }
    short8* hb8 = (short8*)hb1;
    short8 wf[2][4];
#pragma unroll
    for (int kt = 0; kt < 4; ++kt) wf[0][kt] = W1B[kt * 64 + lane];
    float e_h = 0.f;
#pragma unroll
    for (int nt = 0; nt < 8; ++nt) {
      int cur = nt & 1;
      if (nt < 7) {
#pragma unroll
        for (int kt = 0; kt < 4; ++kt)
          wf[cur ^ 1][kt] = W1B[((nt + 1) * 4 + kt) * 64 + lane];
      }
      f32x16 acc;
#pragma unroll
      for (int q = 0; q < 16; ++q) acc[q] = 0.f;
#pragma unroll
      for (int kt = 0; kt < 4; ++kt)
        acc = __builtin_amdgcn_mfma_f32_32x32x16_bf16(a[kt], wf[cur][kt], acc, 0, 0, 0);
#pragma unroll
      for (int reg = 0; reg < 16; ++reg) {
        int row = (reg & 3) + 8 * (reg >> 2) + 4 * kg;  // C/D row map (m74/m101)
        tile[row * 36 + m] = acc[reg];
      }
      int h = nt >> 1, ft = nt & 1;
#pragma unroll
      for (int ktl = 0; ktl < 2; ++ktl) {
        short8 r;
#pragma unroll
        for (int j = 0; j < 8; ++j)
          r[j] = (short)f2bf(tile[(ktl * 16 + kg * 8 + j) * 36 + m]);
        hb8[((((size_t)b * 4 + h) * 32 + mt * 2 + ktl) * 2 + ft) * 64 + lane] = r;
      }
      const float* coeff = (kg ? a1d : a1s) + h * 64 + ft * 32;
      float ep = 0.f;
#pragma unroll
      for (int c4 = 0; c4 < 8; ++c4) {
        float4 tv = *(const float4*)&tile[m * 36 + c4 * 4];
        float4 cv = *(const float4*)&coeff[c4 * 4];
        ep += tv.x * cv.x + tv.y * cv.y + tv.z * cv.z + tv.w * cv.w;
      }
      e_h += ep;
      if (ft) {
        float* p = kg ? e1d : e1s;
        p[((size_t)b * 4 + h) * NN + d0 + m] = e_h;
        e_h = 0.f;
      }
    }
  }
}

// ================= Phase 2: attn1 + fused gemm2 (+e2 dots)
__device__ __forceinline__ void phase2(int i, int t, char* smem,
                                       const unsigned* __restrict__ mask,
                                       const unsigned short* __restrict__ hb1,
                                       const float* __restrict__ e1s,
                                       const float* __restrict__ e1d,
                                       const float* __restrict__ b1,
                                       const short8* __restrict__ W2B,
                                       const float* __restrict__ a2s,
                                       const float* __restrict__ a2d,
                                       unsigned short* __restrict__ hb2,
                                       float* __restrict__ e2s,
                                       float* __restrict__ e2d) {
  float* es = (float*)smem;                             // [0, 8192)
  unsigned* mw = (unsigned*)(smem + 8192);              // [8192, 10240)
  unsigned short* ht = (unsigned short*)(smem + 10240); // [10240, 27136) stride 264
  float* tile2 = (float*)(smem + 27136);                // 2 x 1152 fp32
  int b = (i & 7) * 4 + ((i >> 3) & 3), mt = i >> 5;
  int d0 = mt * 32;
  const float* esrc = e1s + (size_t)b * 4 * NN;
#pragma unroll
  for (int q = 0; q < 8; ++q) es[t + q * 256] = esrc[t + q * 256];
  const unsigned* msrc = mask + (size_t)b * 16 * NN + d0;
  mw[t] = msrc[(t >> 5) * NN + (t & 31)];
  mw[t + 256] = msrc[((t + 256) >> 5) * NN + (t & 31)];
  __syncthreads();
  int h = t >> 6, lane = t & 63, m = lane & 31, kg = lane >> 5;
  float ed = e1d[((size_t)b * 4 + h) * NN + d0 + m];
  const short8* bfr = (const short8*)hb1 + ((size_t)b * 4 + h) * 32 * 2 * 64;
  f32x16 acc0, acc1;
#pragma unroll
  for (int q = 0; q < 16; ++q) { acc0[q] = 0.f; acc1[q] = 0.f; }
  float l = 0.f;
  for (int kt = 0; kt < 32; ++kt) {
    unsigned wv = mw[(kt >> 1) * 32 + m];
    int shift = (kt & 1) * 16 + kg * 8;
    const float* ep = &es[h * NN + kt * 16 + kg * 8];
    short8 a;
#pragma unroll
    for (int j = 0; j < 8; ++j) {
      float sc = ed + ep[j];
      sc = fmaxf(sc, NEG_SLOPE * sc);  // leaky_relu
      float pv = __expf(sc);           // scores O(+-8): no max-shift needed
      pv = ((wv >> (shift + j)) & 1u) ? pv : 0.f;
      l += pv;
      a[j] = (short)f2bf(pv);
    }
    short8 bv0 = bfr[(kt * 2 + 0) * 64 + lane];
    short8 bv1 = bfr[(kt * 2 + 1) * 64 + lane];
    acc0 = __builtin_amdgcn_mfma_f32_32x32x16_bf16(a, bv0, acc0, 0, 0, 0);
    acc1 = __builtin_amdgcn_mfma_f32_32x32x16_bf16(a, bv1, acc1, 0, 0, 0);
  }
  float lf = l + __shfl(l, lane ^ 32, 64);
  float linv = 1.f / lf;
  float bia0 = b1[h * 64 + m];
  float bia1 = b1[h * 64 + 32 + m];
#pragma unroll
  for (int reg = 0; reg < 16; ++reg) {
    int row = (reg & 3) + 8 * (reg >> 2) + 4 * kg;
    float li = __shfl(linv, row, 64);
    float v0 = acc0[reg] * li + bia0;
    v0 = (v0 > 0.f) ? v0 : (__expf(v0) - 1.f);  // ELU
    float v1 = acc1[reg] * li + bia1;
    v1 = (v1 > 0.f) ? v1 : (__expf(v1) - 1.f);
    ht[row * 264 + h * 64 + m] = f2bf(v0);
    ht[row * 264 + h * 64 + 32 + m] = f2bf(v1);
  }
  __syncthreads();
  int w2 = t >> 6;
  if (w2 < 2) {
    int nt = w2;
    short8 wfr[16];
#pragma unroll
    for (int kt = 0; kt < 16; ++kt) wfr[kt] = W2B[(nt * 16 + kt) * 64 + lane];
    f32x16 acc;
#pragma unroll
    for (int q = 0; q < 16; ++q) acc[q] = 0.f;
#pragma unroll
    for (int kt = 0; kt < 16; ++kt) {
      short8 av = *(const short8*)&ht[m * 264 + kt * 16 + kg * 8];
      acc = __builtin_amdgcn_mfma_f32_32x32x16_bf16(av, wfr[kt], acc, 0, 0, 0);
    }
    float* tw = tile2 + nt * 1152;
#pragma unroll
    for (int reg = 0; reg < 16; ++reg) {
      int row = (reg & 3) + 8 * (reg >> 2) + 4 * kg;
      tw[row * 36 + m] = acc[reg];
    }
  }
  __syncthreads();
  if (w2 < 2) {
    const float* tw = tile2 + w2 * 1152;
    short8* hb8 = (short8*)hb2;
#pragma unroll
    for (int ktl = 0; ktl < 2; ++ktl) {
      short8 r;
#pragma unroll
      for (int j = 0; j < 8; ++j)
        r[j] = (short)f2bf(tw[(ktl * 16 + kg * 8 + j) * 36 + m]);
      hb8[(((size_t)b * 32 + mt * 2 + ktl) * 2 + w2) * 64 + lane] = r;
    }
  } else {
    const float* coeff = ((w2 == 2) ? a2s : a2d) + kg * 32;
    const float* tsrc = tile2 + kg * 1152;
    float val = 0.f;
#pragma unroll
    for (int c4 = 0; c4 < 8; ++c4) {
      float4 tv = *(const float4*)&tsrc[m * 36 + c4 * 4];
      float4 cv = *(const float4*)&coeff[c4 * 4];
      val += tv.x * cv.x + tv.y * cv.y + tv.z * cv.z + tv.w * cv.w;
    }
    float tot = val + __shfl(val, lane ^ 32, 64);
    if (kg == 0) {
      float* p = (w2 == 2) ? e2s : e2d;
      p[(size_t)b * NN + d0 + m] = tot;
    }
  }
}

// ================= Phase 3: attn2 -> out
__device__ __forceinline__ void phase3(int i, int t, char* smem,
                                       const unsigned* __restrict__ mask,
                                       const unsigned short* __restrict__ hb2,
                                       const float* __restrict__ e2s,
                                       const float* __restrict__ e2d,
                                       const float* __restrict__ b2,
                                       float* __restrict__ out) {
  float* es2 = (float*)smem;              // [0, 2048)
  unsigned* mw = (unsigned*)(smem + 2048);
  float* cred = (float*)(smem + 4096);    // 8192 fp32
  float* lred = (float*)(smem + 36864);
  float* linvs = (float*)(smem + 37888);
  int b = (i & 7) * 4 + ((i >> 3) & 3);
  int d0 = (i >> 5) * 32;
  es2[t] = e2s[(size_t)b * NN + t];
  es2[t + 256] = e2s[(size_t)b * NN + t + 256];
  const unsigned* msrc = mask + (size_t)b * 16 * NN + d0;
  mw[t] = msrc[(t >> 5) * NN + (t & 31)];
  mw[t + 256] = msrc[((t + 256) >> 5) * NN + (t & 31)];
  __syncthreads();
  int w = t >> 6, lane = t & 63, m = lane & 31, kg = lane >> 5;
  float ed = e2d[(size_t)b * NN + d0 + m];
  const short8* bfr = (const short8*)hb2 + (size_t)b * 32 * 2 * 64;
  f32x16 acc0, acc1;
#pragma unroll
  for (int q = 0; q < 16; ++q) { acc0[q] = 0.f; acc1[q] = 0.f; }
  float l = 0.f;
#pragma unroll
  for (int kk = 0; kk < 8; ++kk) {
    int kt = w * 8 + kk;
    unsigned wv = mw[(kt >> 1) * 32 + m];
    int shift = (kt & 1) * 16 + kg * 8;
    const float* ep = &es2[kt * 16 + kg * 8];
    short8 a;
#pragma unroll
    for (int j = 0; j < 8; ++j) {
      float sc = ed + ep[j];
      sc = fmaxf(sc, NEG_SLOPE * sc);
      float pv = __expf(sc);
      pv = ((wv >> (shift + j)) & 1u) ? pv : 0.f;
      l += pv;
      a[j] = (short)f2bf(pv);
    }
    short8 bv0 = bfr[(kt * 2 + 0) * 64 + lane];
    short8 bv1 = bfr[(kt * 2 + 1) * 64 + lane];
    acc0 = __builtin_amdgcn_mfma_f32_32x32x16_bf16(a, bv0, acc0, 0, 0, 0);
    acc1 = __builtin_amdgcn_mfma_f32_32x32x16_bf16(a, bv1, acc1, 0, 0, 0);
  }
  lred[w * 64 + lane] = l;
#pragma unroll
  for (int reg = 0; reg < 16; ++reg) {
    cred[((w * 2 + 0) * 16 + reg) * 64 + lane] = acc0[reg];
    cred[((w * 2 + 1) * 16 + reg) * 64 + lane] = acc1[reg];
  }
  __syncthreads();
  if (t < 32) {
    float s = 0.f;
#pragma unroll
    for (int q = 0; q < 4; ++q) s += lred[q * 64 + t] + lred[q * 64 + t + 32];
    linvs[t] = 1.f / s;
  }
  __syncthreads();
#pragma unroll
  for (int q = 0; q < 8; ++q) {
    int pos = t + q * 256;
    int nt = pos >> 10;
    int rem = pos & 1023;
    int reg = rem >> 6;
    int ln = rem & 63;
    float v = cred[((0 * 2 + nt) * 16 + reg) * 64 + ln] +
              cred[((1 * 2 + nt) * 16 + reg) * 64 + ln] +
              cred[((2 * 2 + nt) * 16 + reg) * 64 + ln] +
              cred[((3 * 2 + nt) * 16 + reg) * 64 + ln];
    int row = (reg & 3) + 8 * (reg >> 2) + 4 * (ln >> 5);
    int col = nt * 32 + (ln & 31);
    out[((size_t)b * NN + d0 + row) * 64 + col] = v * linvs[row] + b2[col];
  }
}

// ---------------- cooperative megakernel: 2 blocks/CU co-resident (128-VGPR cap)
__global__ __launch_bounds__(256, 2) void k_mega(
    const int* __restrict__ adj, const float* __restrict__ x,
    const short8* __restrict__ W1B, const float* __restrict__ a1s,
    const float* __restrict__ a1d, const float* __restrict__ b1,
    const short8* __restrict__ W2B, const float* __restrict__ a2s,
    const float* __restrict__ a2d, const float* __restrict__ b2,
    unsigned* __restrict__ mask, unsigned short* __restrict__ hb1,
    float* __restrict__ e1s, float* __restrict__ e1d,
    unsigned short* __restrict__ hb2, float* __restrict__ e2s,
    float* __restrict__ e2d, float* __restrict__ out) {
  __shared__ __align__(16) char smem[38016];
  cg::grid_group grid = cg::this_grid();
  int i = blockIdx.x, t = threadIdx.x;
  phase1(i, t, smem, adj, x, W1B, a1s, a1d, mask, hb1, e1s, e1d);
  grid.sync();
  phase2(i, t, smem, mask, hb1, e1s, e1d, b1, W2B, a2s, a2d, hb2, e2s, e2d);
  grid.sync();
  phase3(i, t, smem, mask, hb2, e2s, e2d, b2, out);
}

// ---------------- fallback standalone kernels (R6-equivalent pipeline)
__global__ __launch_bounds__(256) void k_p1(const int* __restrict__ adj,
                                            const float* __restrict__ x,
                                            const short8* __restrict__ W1B,
                                            const float* __restrict__ a1s,
                                            const float* __restrict__ a1d,
                                            unsigned* __restrict__ mask,
                                            unsigned short* __restrict__ hb1,
                                            float* __restrict__ e1s,
                                            float* __restrict__ e1d) {
  __shared__ __align__(16) char smem[4608];
  phase1(blockIdx.x, threadIdx.x, smem, adj, x, W1B, a1s, a1d, mask, hb1, e1s, e1d);
}

__global__ __launch_bounds__(256) void k_p2(
    const unsigned* __restrict__ mask, const unsigned short* __restrict__ hb1,
    const float* __restrict__ e1s, const float* __restrict__ e1d,
    const float* __restrict__ b1, const short8* __restrict__ W2B,
    const float* __restrict__ a2s, const float* __restrict__ a2d,
    unsigned short* __restrict__ hb2, float* __restrict__ e2s,
    float* __restrict__ e2d) {
  __shared__ __align__(16) char smem[36352];
  phase2(blockIdx.x, threadIdx.x, smem, mask, hb1, e1s, e1d, b1, W2B, a2s, a2d,
         hb2, e2s, e2d);
}

__global__ __launch_bounds__(256) void k_p3(const unsigned* __restrict__ mask,
                                            const unsigned short* __restrict__ hb2,
                                            const float* __restrict__ e2s,
                                            const float* __restrict__ e2d,
                                            const float* __restrict__ b2,
                                            float* __restrict__ out) {
  __shared__ __align__(16) char smem[38016];
  phase3(blockIdx.x, threadIdx.x, smem, mask, hb2, e2s, e2d, b2, out);
}

extern "C" void kernel_launch(void* const* d_in, const int* in_sizes, int n_in,
                              void* d_out, int out_size, void* d_ws, size_t ws_size,
                              hipStream_t stream) {
  const float* x = (const float*)d_in[0];
  const int* adj = (const int*)d_in[1];
  const float* W1 = (const float*)d_in[2];
  const float* a1s = (const float*)d_in[3];
  const float* a1d = (const float*)d_in[4];
  const float* b1 = (const float*)d_in[5];
  const float* W2 = (const float*)d_in[6];
  const float* a2s = (const float*)d_in[7];
  const float* a2d = (const float*)d_in[8];
  const float* b2 = (const float*)d_in[9];
  float* out = (float*)d_out;

  char* w = (char*)d_ws;
  short8* W1B = (short8*)w;                                  // 32 KiB
  short8* W2B = (short8*)(w + (64u << 10));                  // 32 KiB
  unsigned* mask = (unsigned*)(w + (128u << 10));            // 1 MiB
  unsigned short* hb1 = (unsigned short*)(w + (2u << 20));   // 8 MiB
  float* e1s = (float*)(w + (12u << 20));                    // 256 KiB
  float* e1d = (float*)(w + (12u << 20) + (256u << 10));     // 256 KiB
  unsigned short* hb2 = (unsigned short*)(w + (16u << 20));  // 2 MiB
  float* e2s = (float*)(w + (20u << 20));                    // 64 KiB
  float* e2d = (float*)(w + (20u << 20) + (64u << 10));      // 64 KiB

  hipLaunchKernelGGL(k_prep, dim3(16), dim3(256), 0, stream, W1, W2, W1B, W2B);

  void* args[18];
  args[0] = (void*)&adj;   args[1] = (void*)&x;    args[2] = (void*)&W1B;
  args[3] = (void*)&a1s;   args[4] = (void*)&a1d;  args[5] = (void*)&b1;
  args[6] = (void*)&W2B;   args[7] = (void*)&a2s;  args[8] = (void*)&a2d;
  args[9] = (void*)&b2;    args[10] = (void*)&mask; args[11] = (void*)&hb1;
  args[12] = (void*)&e1s;  args[13] = (void*)&e1d; args[14] = (void*)&hb2;
  args[15] = (void*)&e2s;  args[16] = (void*)&e2d; args[17] = (void*)&out;
  hipError_t err = hipLaunchCooperativeKernel((const void*)k_mega, dim3(512),
                                              dim3(256), args, 0, stream);
  if (err != hipSuccess) {
    // deterministic fallback: same phases as 3 ordinary kernels (R6-equivalent)
    hipLaunchKernelGGL(k_p1, dim3(512), dim3(256), 0, stream, adj, x, W1B, a1s,
                       a1d, mask, hb1, e1s, e1d);
    hipLaunchKernelGGL(k_p2, dim3(512), dim3(256), 0, stream, mask, hb1, e1s,
                       e1d, b1, W2B, a2s, a2d, hb2, e2s, e2d);
    hipLaunchKernelGGL(k_p3, dim3(512), dim3(256), 0, stream, mask, hb2, e2s,
                       e2d, b2, out);
  }
}

// Round 9
// 126.089 us; speedup vs baseline: 2.0162x; 2.0162x over previous
//
#include <hip/hip_runtime.h>
#include <cstddef>

#define NN 512
#define NEG_SLOPE 0.2f

typedef __attribute__((ext_vector_type(8))) short short8;
typedef __attribute__((ext_vector_type(16))) float f32x16;

__device__ __forceinline__ unsigned short f2bf(float v) {
  unsigned u = __float_as_uint(v);
  return (unsigned short)((u + 0x7FFFu + ((u >> 16) & 1u)) >> 16);
}

// ---------------- K1: fused W1-pack + mask-build + gemm1 (+W2B pack on blocks 0..15).
// All 256 threads pack W1 (L2-hot, coalesced) into LDS bf16 [k][f] (stride 260),
// one barrier. Waves 1-3 then stream adj -> mask tile (HBM-bound, ~5us) while
// wave 0 runs gemm1 reading W1 B-frags from LDS (conflict-free strided u16).
__global__ __launch_bounds__(256) void k_g1m(const int* __restrict__ adj,
                                             const float* __restrict__ x,
                                             const float* __restrict__ W1,
                                             const float* __restrict__ W2,
                                             const float* __restrict__ a1s,
                                             const float* __restrict__ a1d,
                                             unsigned* __restrict__ mask,
                                             unsigned short* __restrict__ hb1,
                                             float* __restrict__ e1s,
                                             float* __restrict__ e1d,
                                             short8* __restrict__ W2B) {
  __shared__ __align__(16) unsigned short w1p[64 * 260];  // 33.3 KB bf16 W1 [k][f]
  __shared__ float tile[32 * 36];                         // 4.6 KB
  int i = blockIdx.x;
  int b = (i & 7) * 4 + ((i >> 3) & 3), mt = i >> 5;  // XCD-affine swizzle
  int d0 = mt * 32;
  int t = threadIdx.x;

  // cooperative W1 pack: thread t handles float4s idx=t+r*256 (fully coalesced)
  const float4* w4 = (const float4*)W1;
#pragma unroll
  for (int r = 0; r < 16; ++r) {
    int idx = t + r * 256;
    float4 v = w4[idx];
    int k = idx >> 6;
    int f0 = (idx & 63) * 4;
    unsigned lo = (unsigned)f2bf(v.x) | ((unsigned)f2bf(v.y) << 16);
    unsigned hi = (unsigned)f2bf(v.z) | ((unsigned)f2bf(v.w) << 16);
    *(uint2*)&w1p[k * 260 + f0] = make_uint2(lo, hi);  // b64, 8B-aligned (520k+8l)
  }
  __syncthreads();

  if (t >= 64) {
    // blocks 0..15: mask waves also emit W2B (16KB total) for k_attn1g2
    if (i < 16 && t < 192) {
      int fi = i * 128 + (t - 64);  // 0..2047
      int unit = fi >> 6, lane = fi & 63;
      int nt = unit >> 4, kt = unit & 15;
      int f = nt * 32 + (lane & 31);
      int k0 = kt * 16 + ((lane >> 5) << 3);
      short8 r;
#pragma unroll
      for (int j = 0; j < 8; ++j) r[j] = (short)f2bf(W2[(k0 + j) * 64 + f]);
      W2B[fi] = r;
    }
    // mask helper: 192 threads cover 512 (w,d) words
    int t2 = t - 64;
    const int* abase = adj + (size_t)b * NN * NN;
    for (int u = t2; u < 512; u += 192) {
      int dl = u & 31, w = u >> 5;
      int d = d0 + dl;
      unsigned wv = 0;
#pragma unroll
      for (int j = 0; j < 32; ++j) {
        int s = w * 32 + j;
        unsigned bit = ((abase[(size_t)s * NN + d] != 0) || (s == d)) ? 1u : 0u;
        wv |= bit << j;
      }
      mask[((size_t)b * 16 + w) * NN + d] = wv;
    }
    return;  // no further barriers in this kernel
  }

  // ---- wave 0: gemm1
  int lane = t, m = lane & 31, kg = lane >> 5;
  const float* xrow = x + ((size_t)b * NN + d0 + m) * 64 + kg * 8;
  short8 a[4];
#pragma unroll
  for (int kt = 0; kt < 4; ++kt) {
    float4 v0 = *(const float4*)(xrow + kt * 16);
    float4 v1 = *(const float4*)(xrow + kt * 16 + 4);
    short8 r;
    r[0] = (short)f2bf(v0.x); r[1] = (short)f2bf(v0.y);
    r[2] = (short)f2bf(v0.z); r[3] = (short)f2bf(v0.w);
    r[4] = (short)f2bf(v1.x); r[5] = (short)f2bf(v1.y);
    r[6] = (short)f2bf(v1.z); r[7] = (short)f2bf(v1.w);
    a[kt] = r;
  }
  short8* hb8 = (short8*)hb1;
  float e_h = 0.f;
#pragma unroll
  for (int nt = 0; nt < 8; ++nt) {
    short8 wfr[4];
#pragma unroll
    for (int kt = 0; kt < 4; ++kt) {
      int base = (kt * 16 + kg * 8) * 260 + nt * 32 + m;
      short8 r;
#pragma unroll
      for (int j = 0; j < 8; ++j) r[j] = (short)w1p[base + j * 260];
      wfr[kt] = r;
    }
    f32x16 acc;
#pragma unroll
    for (int q = 0; q < 16; ++q) acc[q] = 0.f;
#pragma unroll
    for (int kt = 0; kt < 4; ++kt)
      acc = __builtin_amdgcn_mfma_f32_32x32x16_bf16(a[kt], wfr[kt], acc, 0, 0, 0);
#pragma unroll
    for (int reg = 0; reg < 16; ++reg) {
      int row = (reg & 3) + 8 * (reg >> 2) + 4 * kg;  // C/D row map (m74/m101)
      tile[row * 36 + m] = acc[reg];
    }
    int h = nt >> 1, ft = nt & 1;
#pragma unroll
    for (int ktl = 0; ktl < 2; ++ktl) {
      short8 r;
#pragma unroll
      for (int j = 0; j < 8; ++j)
        r[j] = (short)f2bf(tile[(ktl * 16 + kg * 8 + j) * 36 + m]);
      hb8[((((size_t)b * 4 + h) * 32 + mt * 2 + ktl) * 2 + ft) * 64 + lane] = r;
    }
    const float* coeff = (kg ? a1d : a1s) + h * 64 + ft * 32;
    float ep = 0.f;
#pragma unroll
    for (int c4 = 0; c4 < 8; ++c4) {
      float4 tv = *(const float4*)&tile[m * 36 + c4 * 4];
      float4 cv = *(const float4*)&coeff[c4 * 4];
      ep += tv.x * cv.x + tv.y * cv.y + tv.z * cv.z + tv.w * cv.w;
    }
    e_h += ep;
    if (ft) {
      float* p = kg ? e1d : e1s;
      p[((size_t)b * 4 + h) * NN + d0 + m] = e_h;
      e_h = 0.f;
    }
  }
}

// ---------------- K2: fused layer-1 attention + layer-2 GEMM (+e2 dots). (R6 verbatim)
__global__ __launch_bounds__(256) void k_attn1g2(const unsigned* __restrict__ mask,
                                                 const unsigned short* __restrict__ hb1,
                                                 const float* __restrict__ e1s,
                                                 const float* __restrict__ e1d,
                                                 const float* __restrict__ b1,
                                                 const short8* __restrict__ W2B,
                                                 const float* __restrict__ a2s,
                                                 const float* __restrict__ a2d,
                                                 unsigned short* __restrict__ hb2,
                                                 float* __restrict__ e2s,
                                                 float* __restrict__ e2d) {
  __shared__ float es[4 * NN];             // 8 KB
  __shared__ unsigned mw[16 * 32];         // 2 KB
  __shared__ unsigned short ht[32 * 264];  // 16.5 KB
  __shared__ float tile2[2][32 * 36];      // 9.2 KB
  int i = blockIdx.x;
  int b = (i & 7) * 4 + ((i >> 3) & 3), mt = i >> 5;  // XCD-affine swizzle
  int d0 = mt * 32;
  int t = threadIdx.x;
  const float* esrc = e1s + (size_t)b * 4 * NN;
#pragma unroll
  for (int q = 0; q < 8; ++q) es[t + q * 256] = esrc[t + q * 256];
  const unsigned* msrc = mask + (size_t)b * 16 * NN + d0;
  mw[t] = msrc[(t >> 5) * NN + (t & 31)];
  {
    int idx = t + 256;
    mw[idx] = msrc[(idx >> 5) * NN + (idx & 31)];
  }
  __syncthreads();
  int h = t >> 6, lane = t & 63, m = lane & 31, kg = lane >> 5;
  float ed = e1d[((size_t)b * 4 + h) * NN + d0 + m];
  const short8* bfr = (const short8*)hb1 + ((size_t)b * 4 + h) * 32 * 2 * 64;
  f32x16 acc0, acc1;
#pragma unroll
  for (int q = 0; q < 16; ++q) { acc0[q] = 0.f; acc1[q] = 0.f; }
  float l = 0.f;
  for (int kt = 0; kt < 32; ++kt) {
    unsigned wv = mw[(kt >> 1) * 32 + m];
    int shift = (kt & 1) * 16 + kg * 8;
    const float* ep = &es[h * NN + kt * 16 + kg * 8];
    short8 a;
#pragma unroll
    for (int j = 0; j < 8; ++j) {
      float sc = ed + ep[j];
      sc = fmaxf(sc, NEG_SLOPE * sc);  // leaky_relu
      float pv = __expf(sc);           // scores O(+-8): no max-shift needed
      pv = ((wv >> (shift + j)) & 1u) ? pv : 0.f;
      l += pv;
      a[j] = (short)f2bf(pv);
    }
    short8 bv0 = bfr[(kt * 2 + 0) * 64 + lane];
    short8 bv1 = bfr[(kt * 2 + 1) * 64 + lane];
    acc0 = __builtin_amdgcn_mfma_f32_32x32x16_bf16(a, bv0, acc0, 0, 0, 0);
    acc1 = __builtin_amdgcn_mfma_f32_32x32x16_bf16(a, bv1, acc1, 0, 0, 0);
  }
  float lf = l + __shfl(l, lane ^ 32, 64);
  float linv = 1.f / lf;
  float bia0 = b1[h * 64 + m];
  float bia1 = b1[h * 64 + 32 + m];
#pragma unroll
  for (int reg = 0; reg < 16; ++reg) {
    int row = (reg & 3) + 8 * (reg >> 2) + 4 * kg;  // C/D row map
    float li = __shfl(linv, row, 64);
    float v0 = acc0[reg] * li + bia0;
    v0 = (v0 > 0.f) ? v0 : (__expf(v0) - 1.f);  // ELU
    float v1 = acc1[reg] * li + bia1;
    v1 = (v1 > 0.f) ? v1 : (__expf(v1) - 1.f);
    ht[row * 264 + h * 64 + m] = f2bf(v0);
    ht[row * 264 + h * 64 + 32 + m] = f2bf(v1);
  }
  __syncthreads();
  int w2 = t >> 6;
  if (w2 < 2) {
    int nt = w2;
    short8 wfr[16];
#pragma unroll
    for (int kt = 0; kt < 16; ++kt) wfr[kt] = W2B[(nt * 16 + kt) * 64 + lane];
    f32x16 acc;
#pragma unroll
    for (int q = 0; q < 16; ++q) acc[q] = 0.f;
#pragma unroll
    for (int kt = 0; kt < 16; ++kt) {
      short8 av = *(const short8*)&ht[m * 264 + kt * 16 + kg * 8];
      acc = __builtin_amdgcn_mfma_f32_32x32x16_bf16(av, wfr[kt], acc, 0, 0, 0);
    }
    float* tw = tile2[nt];
#pragma unroll
    for (int reg = 0; reg < 16; ++reg) {
      int row = (reg & 3) + 8 * (reg >> 2) + 4 * kg;
      tw[row * 36 + m] = acc[reg];
    }
  }
  __syncthreads();
  if (w2 < 2) {
    const float* tw = tile2[w2];
    short8* hb8 = (short8*)hb2;
#pragma unroll
    for (int ktl = 0; ktl < 2; ++ktl) {
      short8 r;
#pragma unroll
      for (int j = 0; j < 8; ++j)
        r[j] = (short)f2bf(tw[(ktl * 16 + kg * 8 + j) * 36 + m]);
      hb8[(((size_t)b * 32 + mt * 2 + ktl) * 2 + w2) * 64 + lane] = r;
    }
  } else {
    const float* coeff = ((w2 == 2) ? a2s : a2d) + kg * 32;
    const float* tsrc = tile2[kg];
    float val = 0.f;
#pragma unroll
    for (int c4 = 0; c4 < 8; ++c4) {
      float4 tv = *(const float4*)&tsrc[m * 36 + c4 * 4];
      float4 cv = *(const float4*)&coeff[c4 * 4];
      val += tv.x * cv.x + tv.y * cv.y + tv.z * cv.z + tv.w * cv.w;
    }
    float tot = val + __shfl(val, lane ^ 32, 64);
    if (kg == 0) {
      float* p = (w2 == 2) ? e2s : e2d;
      p[(size_t)b * NN + d0 + m] = tot;
    }
  }
}

// ---------------- K3: layer-2 attention via MFMA, 4 waves split K, LDS reduce. (R6 verbatim)
__global__ __launch_bounds__(256) void k_attn2(const unsigned* __restrict__ mask,
                                               const unsigned short* __restrict__ hb2,
                                               const float* __restrict__ e2s,
                                               const float* __restrict__ e2d,
                                               const float* __restrict__ b2,
                                               float* __restrict__ out) {
  __shared__ float es[NN];
  __shared__ unsigned mw[16 * 32];
  __shared__ float cred[4][2][16][64];
  __shared__ float lred[4][64];
  __shared__ float linv_s[32];
  int i = blockIdx.x;
  int b = (i & 7) * 4 + ((i >> 3) & 3);  // XCD-affine swizzle
  int d0 = (i >> 5) * 32;
  int t = threadIdx.x;
  es[t] = e2s[(size_t)b * NN + t];
  es[t + 256] = e2s[(size_t)b * NN + t + 256];
  const unsigned* msrc = mask + (size_t)b * 16 * NN + d0;
  mw[t] = msrc[(t >> 5) * NN + (t & 31)];
  {
    int idx = t + 256;
    mw[idx] = msrc[(idx >> 5) * NN + (idx & 31)];
  }
  __syncthreads();
  int w = t >> 6, lane = t & 63, m = lane & 31, kg = lane >> 5;
  float ed = e2d[(size_t)b * NN + d0 + m];
  const short8* bfr = (const short8*)hb2 + (size_t)b * 32 * 2 * 64;
  f32x16 acc0, acc1;
#pragma unroll
  for (int q = 0; q < 16; ++q) { acc0[q] = 0.f; acc1[q] = 0.f; }
  float l = 0.f;
#pragma unroll
  for (int kk = 0; kk < 8; ++kk) {
    int kt = w * 8 + kk;
    unsigned wv = mw[(kt >> 1) * 32 + m];
    int shift = (kt & 1) * 16 + kg * 8;
    const float* ep = &es[kt * 16 + kg * 8];
    short8 a;
#pragma unroll
    for (int j = 0; j < 8; ++j) {
      float sc = ed + ep[j];
      sc = fmaxf(sc, NEG_SLOPE * sc);
      float pv = __expf(sc);
      pv = ((wv >> (shift + j)) & 1u) ? pv : 0.f;
      l += pv;
      a[j] = (short)f2bf(pv);
    }
    short8 bv0 = bfr[(kt * 2 + 0) * 64 + lane];
    short8 bv1 = bfr[(kt * 2 + 1) * 64 + lane];
    acc0 = __builtin_amdgcn_mfma_f32_32x32x16_bf16(a, bv0, acc0, 0, 0, 0);
    acc1 = __builtin_amdgcn_mfma_f32_32x32x16_bf16(a, bv1, acc1, 0, 0, 0);
  }
  lred[w][lane] = l;
#pragma unroll
  for (int reg = 0; reg < 16; ++reg) {
    cred[w][0][reg][lane] = acc0[reg];
    cred[w][1][reg][lane] = acc1[reg];
  }
  __syncthreads();
  if (t < 32) {
    float s = 0.f;
#pragma unroll
    for (int q = 0; q < 4; ++q) s += lred[q][t] + lred[q][t + 32];
    linv_s[t] = 1.f / s;
  }
  __syncthreads();
#pragma unroll
  for (int q = 0; q < 8; ++q) {
    int pos = t + q * 256;
    int nt = pos >> 10;
    int rem = pos & 1023;
    int reg = rem >> 6;
    int ln = rem & 63;
    float v = cred[0][nt][reg][ln] + cred[1][nt][reg][ln] +
              cred[2][nt][reg][ln] + cred[3][nt][reg][ln];
    int row = (reg & 3) + 8 * (reg >> 2) + 4 * (ln >> 5);
    int col = nt * 32 + (ln & 31);
    out[((size_t)b * NN + d0 + row) * 64 + col] = v * linv_s[row] + b2[col];
  }
}

extern "C" void kernel_launch(void* const* d_in, const int* in_sizes, int n_in,
                              void* d_out, int out_size, void* d_ws, size_t ws_size,
                              hipStream_t stream) {
  const float* x = (const float*)d_in[0];
  const int* adj = (const int*)d_in[1];
  const float* W1 = (const float*)d_in[2];
  const float* a1s = (const float*)d_in[3];
  const float* a1d = (const float*)d_in[4];
  const float* b1 = (const float*)d_in[5];
  const float* W2 = (const float*)d_in[6];
  const float* a2s = (const float*)d_in[7];
  const float* a2d = (const float*)d_in[8];
  const float* b2 = (const float*)d_in[9];
  float* out = (float*)d_out;

  char* w = (char*)d_ws;
  short8* W2B = (short8*)w;                                  // 32 KiB
  unsigned* mask = (unsigned*)(w + (128u << 10));            // 1 MiB
  unsigned short* hb1 = (unsigned short*)(w + (2u << 20));   // 8 MiB
  float* e1s = (float*)(w + (12u << 20));                    // 256 KiB
  float* e1d = (float*)(w + (12u << 20) + (256u << 10));     // 256 KiB
  unsigned short* hb2 = (unsigned short*)(w + (16u << 20));  // 2 MiB
  float* e2s = (float*)(w + (20u << 20));                    // 64 KiB
  float* e2d = (float*)(w + (20u << 20) + (64u << 10));      // 64 KiB

  hipLaunchKernelGGL(k_g1m, dim3(512), dim3(256), 0, stream, adj, x, W1, W2,
                     a1s, a1d, mask, hb1, e1s, e1d, W2B);
  hipLaunchKernelGGL(k_attn1g2, dim3(512), dim3(256), 0, stream, mask, hb1,
                     e1s, e1d, b1, W2B, a2s, a2d, hb2, e2s, e2d);
  hipLaunchKernelGGL(k_attn2, dim3(512), dim3(256), 0, stream, mask, hb2, e2s,
                     e2d, b2, out);
}

// Round 10
// 122.617 us; speedup vs baseline: 2.0733x; 1.0283x over previous
//
#include <hip/hip_runtime.h>
#include <cstddef>

#define NN 512
#define NEG_SLOPE 0.2f

typedef __attribute__((ext_vector_type(8))) short short8;
typedef __attribute__((ext_vector_type(16))) float f32x16;

__device__ __forceinline__ unsigned short f2bf(float v) {
  unsigned u = __float_as_uint(v);
  return (unsigned short)((u + 0x7FFFu + ((u >> 16) & 1u)) >> 16);
}

// ---------------- K0: tiny weight prep. Blocks 0..7: W1 -> B-frags (8 n-tiles);
// blocks 8..15: W2 -> B-frags (2 n-tiles).
__global__ __launch_bounds__(256) void k_prep(const float* __restrict__ W1,
                                              const float* __restrict__ W2,
                                              short8* __restrict__ W1B,
                                              short8* __restrict__ W2B) {
  int blk = blockIdx.x, t = threadIdx.x;
  if (blk < 8) {
    int idx = blk * 256 + t;  // 0..2047
    int unit = idx >> 6, lane = idx & 63;
    int nt = unit >> 2, kt = unit & 3;
    int f = nt * 32 + (lane & 31);
    int k0 = kt * 16 + ((lane >> 5) << 3);
    short8 r;
#pragma unroll
    for (int j = 0; j < 8; ++j) r[j] = (short)f2bf(W1[(k0 + j) * 256 + f]);
    W1B[idx] = r;
  } else {
    int idx = (blk - 8) * 256 + t;  // 0..2047
    int unit = idx >> 6, lane = idx & 63;
    int nt = unit >> 4, kt = unit & 15;
    int f = nt * 32 + (lane & 31);
    int k0 = kt * 16 + ((lane >> 5) << 3);
    short8 r;
#pragma unroll
    for (int j = 0; j < 8; ++j) r[j] = (short)f2bf(W2[(k0 + j) * 64 + f]);
    W2B[idx] = r;
  }
}

// ---------------- K1: fused mask-build + gemm1.
// Block (b,mt), 256 threads, no barriers. Waves 1..3 build the mask tile from adj
// (overlaps the 33.5MB adj scan with compute). Wave 0: coalesced W1B frags (dbuf),
// packs x in-register, 32 MFMAs, LDS-bounce to hb1 B-frags + fp32 e1 dots.
__global__ __launch_bounds__(256) void k_g1m(const int* __restrict__ adj,
                                             const float* __restrict__ x,
                                             const short8* __restrict__ W1B,
                                             const float* __restrict__ a1s,
                                             const float* __restrict__ a1d,
                                             unsigned* __restrict__ mask,
                                             unsigned short* __restrict__ hb1,
                                             float* __restrict__ e1s,
                                             float* __restrict__ e1d) {
  __shared__ float tile[32 * 36];  // stride 36: 16B-aligned rows for e-dot b128
  int i = blockIdx.x;
  int b = (i & 7) * 4 + ((i >> 3) & 3), mt = i >> 5;  // XCD-affine swizzle
  int d0 = mt * 32;
  int t = threadIdx.x;

  if (t >= 64) {
    // mask helper: 192 threads cover 512 (w,d) words
    int t2 = t - 64;
    const int* abase = adj + (size_t)b * NN * NN;
    for (int u = t2; u < 512; u += 192) {
      int dl = u & 31, w = u >> 5;
      int d = d0 + dl;
      unsigned wv = 0;
#pragma unroll
      for (int j = 0; j < 32; ++j) {
        int s = w * 32 + j;
        unsigned bit = ((abase[(size_t)s * NN + d] != 0) || (s == d)) ? 1u : 0u;
        wv |= bit << j;
      }
      mask[((size_t)b * 16 + w) * NN + d] = wv;
    }
    return;  // no barriers in this kernel
  }

  // ---- wave 0: gemm1
  int lane = t, m = lane & 31, kg = lane >> 5;
  const float* xrow = x + ((size_t)b * NN + d0 + m) * 64 + kg * 8;
  short8 a[4];
#pragma unroll
  for (int kt = 0; kt < 4; ++kt) {
    float4 v0 = *(const float4*)(xrow + kt * 16);
    float4 v1 = *(const float4*)(xrow + kt * 16 + 4);
    short8 r;
    r[0] = (short)f2bf(v0.x); r[1] = (short)f2bf(v0.y);
    r[2] = (short)f2bf(v0.z); r[3] = (short)f2bf(v0.w);
    r[4] = (short)f2bf(v1.x); r[5] = (short)f2bf(v1.y);
    r[6] = (short)f2bf(v1.z); r[7] = (short)f2bf(v1.w);
    a[kt] = r;
  }
  short8* hb8 = (short8*)hb1;
  // double-buffered coalesced W1B fragment loads
  short8 wf[2][4];
#pragma unroll
  for (int kt = 0; kt < 4; ++kt) wf[0][kt] = W1B[kt * 64 + lane];
  float e_h = 0.f;
#pragma unroll
  for (int nt = 0; nt < 8; ++nt) {
    int cur = nt & 1;
    if (nt < 7) {
#pragma unroll
      for (int kt = 0; kt < 4; ++kt)
        wf[cur ^ 1][kt] = W1B[((nt + 1) * 4 + kt) * 64 + lane];
    }
    f32x16 acc;
#pragma unroll
    for (int q = 0; q < 16; ++q) acc[q] = 0.f;
#pragma unroll
    for (int kt = 0; kt < 4; ++kt)
      acc = __builtin_amdgcn_mfma_f32_32x32x16_bf16(a[kt], wf[cur][kt], acc, 0, 0, 0);
#pragma unroll
    for (int reg = 0; reg < 16; ++reg) {
      int row = (reg & 3) + 8 * (reg >> 2) + 4 * kg;  // C/D row map (m74/m101)
      tile[row * 36 + m] = acc[reg];
    }
    // hb1 B-frag pack (intra-wave LDS RAW: compiler orders via lgkmcnt)
    int h = nt >> 1, ft = nt & 1;
#pragma unroll
    for (int ktl = 0; ktl < 2; ++ktl) {
      short8 r;
#pragma unroll
      for (int j = 0; j < 8; ++j)
        r[j] = (short)f2bf(tile[(ktl * 16 + kg * 8 + j) * 36 + m]);
      hb8[((((size_t)b * 4 + h) * 32 + mt * 2 + ktl) * 2 + ft) * 64 + lane] = r;
    }
    // fp32 e-dot on the tile: lane (row=m, which=kg)
    const float* coeff = (kg ? a1d : a1s) + h * 64 + ft * 32;
    float ep = 0.f;
#pragma unroll
    for (int c4 = 0; c4 < 8; ++c4) {
      float4 tv = *(const float4*)&tile[m * 36 + c4 * 4];
      float4 cv = *(const float4*)&coeff[c4 * 4];
      ep += tv.x * cv.x + tv.y * cv.y + tv.z * cv.z + tv.w * cv.w;
    }
    e_h += ep;
    if (ft) {
      float* p = kg ? e1d : e1s;
      p[((size_t)b * 4 + h) * NN + d0 + m] = e_h;
      e_h = 0.f;
    }
  }
}

// ---------------- K2: fused layer-1 attention + layer-2 GEMM (+e2 dots).
__global__ __launch_bounds__(256) void k_attn1g2(const unsigned* __restrict__ mask,
                                                 const unsigned short* __restrict__ hb1,
                                                 const float* __restrict__ e1s,
                                                 const float* __restrict__ e1d,
                                                 const float* __restrict__ b1,
                                                 const short8* __restrict__ W2B,
                                                 const float* __restrict__ a2s,
                                                 const float* __restrict__ a2d,
                                                 unsigned short* __restrict__ hb2,
                                                 float* __restrict__ e2s,
                                                 float* __restrict__ e2d) {
  __shared__ float es[4 * NN];             // 8 KB
  __shared__ unsigned mw[16 * 32];         // 2 KB
  __shared__ unsigned short ht[32 * 264];  // 16.5 KB
  __shared__ float tile2[2][32 * 36];      // 9.2 KB
  int i = blockIdx.x;
  int b = (i & 7) * 4 + ((i >> 3) & 3), mt = i >> 5;  // XCD-affine swizzle
  int d0 = mt * 32;
  int t = threadIdx.x;
  const float* esrc = e1s + (size_t)b * 4 * NN;
#pragma unroll
  for (int q = 0; q < 8; ++q) es[t + q * 256] = esrc[t + q * 256];
  const unsigned* msrc = mask + (size_t)b * 16 * NN + d0;
  mw[t] = msrc[(t >> 5) * NN + (t & 31)];
  {
    int idx = t + 256;
    mw[idx] = msrc[(idx >> 5) * NN + (idx & 31)];
  }
  __syncthreads();
  int h = t >> 6, lane = t & 63, m = lane & 31, kg = lane >> 5;
  float ed = e1d[((size_t)b * 4 + h) * NN + d0 + m];
  const short8* bfr = (const short8*)hb1 + ((size_t)b * 4 + h) * 32 * 2 * 64;
  f32x16 acc0, acc1;
#pragma unroll
  for (int q = 0; q < 16; ++q) { acc0[q] = 0.f; acc1[q] = 0.f; }
  float l = 0.f;
  for (int kt = 0; kt < 32; ++kt) {
    unsigned wv = mw[(kt >> 1) * 32 + m];
    int shift = (kt & 1) * 16 + kg * 8;
    const float* ep = &es[h * NN + kt * 16 + kg * 8];
    short8 a;
#pragma unroll
    for (int j = 0; j < 8; ++j) {
      float sc = ed + ep[j];
      sc = fmaxf(sc, NEG_SLOPE * sc);  // leaky_relu
      float pv = __expf(sc);           // scores O(+-8): no max-shift needed
      pv = ((wv >> (shift + j)) & 1u) ? pv : 0.f;
      l += pv;
      a[j] = (short)f2bf(pv);
    }
    short8 bv0 = bfr[(kt * 2 + 0) * 64 + lane];
    short8 bv1 = bfr[(kt * 2 + 1) * 64 + lane];
    acc0 = __builtin_amdgcn_mfma_f32_32x32x16_bf16(a, bv0, acc0, 0, 0, 0);
    acc1 = __builtin_amdgcn_mfma_f32_32x32x16_bf16(a, bv1, acc1, 0, 0, 0);
  }
  float lf = l + __shfl(l, lane ^ 32, 64);
  float linv = 1.f / lf;
  float bia0 = b1[h * 64 + m];
  float bia1 = b1[h * 64 + 32 + m];
#pragma unroll
  for (int reg = 0; reg < 16; ++reg) {
    int row = (reg & 3) + 8 * (reg >> 2) + 4 * kg;  // C/D row map
    float li = __shfl(linv, row, 64);
    float v0 = acc0[reg] * li + bia0;
    v0 = (v0 > 0.f) ? v0 : (__expf(v0) - 1.f);  // ELU
    float v1 = acc1[reg] * li + bia1;
    v1 = (v1 > 0.f) ? v1 : (__expf(v1) - 1.f);
    ht[row * 264 + h * 64 + m] = f2bf(v0);
    ht[row * 264 + h * 64 + 32 + m] = f2bf(v1);
  }
  __syncthreads();
  int w2 = t >> 6;
  if (w2 < 2) {
    int nt = w2;
    short8 wfr[16];
#pragma unroll
    for (int kt = 0; kt < 16; ++kt) wfr[kt] = W2B[(nt * 16 + kt) * 64 + lane];
    f32x16 acc;
#pragma unroll
    for (int q = 0; q < 16; ++q) acc[q] = 0.f;
#pragma unroll
    for (int kt = 0; kt < 16; ++kt) {
      short8 av = *(const short8*)&ht[m * 264 + kt * 16 + kg * 8];
      acc = __builtin_amdgcn_mfma_f32_32x32x16_bf16(av, wfr[kt], acc, 0, 0, 0);
    }
    float* tw = tile2[nt];
#pragma unroll
    for (int reg = 0; reg < 16; ++reg) {
      int row = (reg & 3) + 8 * (reg >> 2) + 4 * kg;
      tw[row * 36 + m] = acc[reg];
    }
  }
  __syncthreads();
  if (w2 < 2) {
    const float* tw = tile2[w2];
    short8* hb8 = (short8*)hb2;
#pragma unroll
    for (int ktl = 0; ktl < 2; ++ktl) {
      short8 r;
#pragma unroll
      for (int j = 0; j < 8; ++j)
        r[j] = (short)f2bf(tw[(ktl * 16 + kg * 8 + j) * 36 + m]);
      hb8[(((size_t)b * 32 + mt * 2 + ktl) * 2 + w2) * 64 + lane] = r;
    }
  } else {
    const float* coeff = ((w2 == 2) ? a2s : a2d) + kg * 32;
    const float* tsrc = tile2[kg];
    float val = 0.f;
#pragma unroll
    for (int c4 = 0; c4 < 8; ++c4) {
      float4 tv = *(const float4*)&tsrc[m * 36 + c4 * 4];
      float4 cv = *(const float4*)&coeff[c4 * 4];
      val += tv.x * cv.x + tv.y * cv.y + tv.z * cv.z + tv.w * cv.w;
    }
    float tot = val + __shfl(val, lane ^ 32, 64);
    if (kg == 0) {
      float* p = (w2 == 2) ? e2s : e2d;
      p[(size_t)b * NN + d0 + m] = tot;
    }
  }
}

// ---------------- K3: layer-2 attention via MFMA, 4 waves split K, LDS reduce
__global__ __launch_bounds__(256) void k_attn2(const unsigned* __restrict__ mask,
                                               const unsigned short* __restrict__ hb2,
                                               const float* __restrict__ e2s,
                                               const float* __restrict__ e2d,
                                               const float* __restrict__ b2,
                                               float* __restrict__ out) {
  __shared__ float es[NN];
  __shared__ unsigned mw[16 * 32];
  __shared__ float cred[4][2][16][64];
  __shared__ float lred[4][64];
  __shared__ float linv_s[32];
  int i = blockIdx.x;
  int b = (i & 7) * 4 + ((i >> 3) & 3);  // XCD-affine swizzle
  int d0 = (i >> 5) * 32;
  int t = threadIdx.x;
  es[t] = e2s[(size_t)b * NN + t];
  es[t + 256] = e2s[(size_t)b * NN + t + 256];
  const unsigned* msrc = mask + (size_t)b * 16 * NN + d0;
  mw[t] = msrc[(t >> 5) * NN + (t & 31)];
  {
    int idx = t + 256;
    mw[idx] = msrc[(idx >> 5) * NN + (idx & 31)];
  }
  __syncthreads();
  int w = t >> 6, lane = t & 63, m = lane & 31, kg = lane >> 5;
  float ed = e2d[(size_t)b * NN + d0 + m];
  const short8* bfr = (const short8*)hb2 + (size_t)b * 32 * 2 * 64;
  f32x16 acc0, acc1;
#pragma unroll
  for (int q = 0; q < 16; ++q) { acc0[q] = 0.f; acc1[q] = 0.f; }
  float l = 0.f;
#pragma unroll
  for (int kk = 0; kk < 8; ++kk) {
    int kt = w * 8 + kk;
    unsigned wv = mw[(kt >> 1) * 32 + m];
    int shift = (kt & 1) * 16 + kg * 8;
    const float* ep = &es[kt * 16 + kg * 8];
    short8 a;
#pragma unroll
    for (int j = 0; j < 8; ++j) {
      float sc = ed + ep[j];
      sc = fmaxf(sc, NEG_SLOPE * sc);
      float pv = __expf(sc);
      pv = ((wv >> (shift + j)) & 1u) ? pv : 0.f;
      l += pv;
      a[j] = (short)f2bf(pv);
    }
    short8 bv0 = bfr[(kt * 2 + 0) * 64 + lane];
    short8 bv1 = bfr[(kt * 2 + 1) * 64 + lane];
    acc0 = __builtin_amdgcn_mfma_f32_32x32x16_bf16(a, bv0, acc0, 0, 0, 0);
    acc1 = __builtin_amdgcn_mfma_f32_32x32x16_bf16(a, bv1, acc1, 0, 0, 0);
  }
  lred[w][lane] = l;
#pragma unroll
  for (int reg = 0; reg < 16; ++reg) {
    cred[w][0][reg][lane] = acc0[reg];
    cred[w][1][reg][lane] = acc1[reg];
  }
  __syncthreads();
  if (t < 32) {
    float s = 0.f;
#pragma unroll
    for (int q = 0; q < 4; ++q) s += lred[q][t] + lred[q][t + 32];
    linv_s[t] = 1.f / s;
  }
  __syncthreads();
#pragma unroll
  for (int q = 0; q < 8; ++q) {
    int pos = t + q * 256;
    int nt = pos >> 10;
    int rem = pos & 1023;
    int reg = rem >> 6;
    int ln = rem & 63;
    float v = cred[0][nt][reg][ln] + cred[1][nt][reg][ln] +
              cred[2][nt][reg][ln] + cred[3][nt][reg][ln];
    int row = (reg & 3) + 8 * (reg >> 2) + 4 * (ln >> 5);
    int col = nt * 32 + (ln & 31);
    out[((size_t)b * NN + d0 + row) * 64 + col] = v * linv_s[row] + b2[col];
  }
}

extern "C" void kernel_launch(void* const* d_in, const int* in_sizes, int n_in,
                              void* d_out, int out_size, void* d_ws, size_t ws_size,
                              hipStream_t stream) {
  const float* x = (const float*)d_in[0];
  const int* adj = (const int*)d_in[1];
  const float* W1 = (const float*)d_in[2];
  const float* a1s = (const float*)d_in[3];
  const float* a1d = (const float*)d_in[4];
  const float* b1 = (const float*)d_in[5];
  const float* W2 = (const float*)d_in[6];
  const float* a2s = (const float*)d_in[7];
  const float* a2d = (const float*)d_in[8];
  const float* b2 = (const float*)d_in[9];
  float* out = (float*)d_out;

  char* w = (char*)d_ws;
  short8* W1B = (short8*)(w + (3u << 20));                   // 32 KiB
  short8* W2B = (short8*)(w + (3u << 20) + (64u << 10));     // 32 KiB
  unsigned* mask = (unsigned*)w;                             // 1 MiB
  unsigned short* hb1 = (unsigned short*)(w + (4u << 20));   // 8 MiB
  float* e1s = (float*)(w + (12u << 20));                    // 256 KiB
  float* e1d = (float*)(w + (12u << 20) + (256u << 10));     // 256 KiB
  unsigned short* hb2 = (unsigned short*)(w + (21u << 20));  // 2 MiB
  float* e2s = (float*)(w + (23u << 20));                    // 64 KiB
  float* e2d = (float*)(w + (23u << 20) + (64u << 10));      // 64 KiB

  hipLaunchKernelGGL(k_prep, dim3(16), dim3(256), 0, stream, W1, W2, W1B, W2B);
  hipLaunchKernelGGL(k_g1m, dim3(512), dim3(256), 0, stream, adj, x, W1B, a1s,
                     a1d, mask, hb1, e1s, e1d);
  hipLaunchKernelGGL(k_attn1g2, dim3(512), dim3(256), 0, stream, mask, hb1,
                     e1s, e1d, b1, W2B, a2s, a2d, hb2, e2s, e2d);
  hipLaunchKernelGGL(k_attn2, dim3(512), dim3(256), 0, stream, mask, hb2, e2s,
                     e2d, b2, out);
}